// Round 13
// baseline (259.631 us; speedup 1.0000x reference)
//
#include <hip/hip_runtime.h>

// ResidualNetwork forward, MI355X (gfx950).
// Round 13: 32x32x16_f16 MFMA (native rate ~8-9cyc, vs legacy 16x16x16 which
// r12 measured at ~17cyc/instr). 32 points per tile, 1 MFMA per layer.
// D->B relayout problem (rows split across half-waves) solved with ZERO
// cross-lane ops: use D's packed dwords directly as the next B fragment and
// PERMUTE THE K-AXIS OF THE WEIGHTS instead (prepack-time):
//   B k-slot (g,j) holds h row sigma = (j&3) + 8*(j>>2) + 4g
//   => A[m][k] = W[sigma(k)][m]. Summation over k is order-permuted only.
// relu+cvt = 4 v_pk_max_f32 + 4 v_cvt_pkrtz = 8 VALU per layer transition.
// Bias/ones-row trick as r11/r12: ones row = h row 10 -> k-slot 6 (g=0,j=6).
// Dead rows m>=11: A rows zero -> D rows 11..31 exactly 0 -> no garbage
// propagation; B k-slots with sigma>=11 carry those zeros.
// Budget/SIMD: MFMA 128 tiles x 34 x ~8.5cyc = 37k cyc (15us); VALU ~54k
// (22us); ILP=2 tile-chains vs latency at 2 waves/SIMD (VGPR ~240).

#define NPTS 4194304
#define NBLK 2048
#define NWAVES (NBLK * 4)           // 8192
#define NTILES (NPTS / 32)          // 131072
#define TPW (NTILES / NWAVES)       // 16 tiles per wave
#define NMM 34
#define ILP 2

typedef _Float16 h8 __attribute__((ext_vector_type(8)));
typedef float v16f __attribute__((ext_vector_type(16)));
typedef unsigned u4v __attribute__((ext_vector_type(4)));

__device__ __forceinline__ v16f mm(h8 a, h8 b, v16f c) {
    return __builtin_amdgcn_mfma_f32_32x32x16_f16(a, b, c, 0, 0, 0);
}
__device__ __forceinline__ unsigned pkrtz(float a, float b) {
    return __builtin_bit_cast(unsigned, __builtin_amdgcn_cvt_pkrtz(a, b));
}
// relu + pack-cvt; output IS the next layer's B fragment (sigma-order).
__device__ __forceinline__ h8 rc(v16f d) {
    u4v u;
    u.x = pkrtz(fmaxf(d[0], 0.f), fmaxf(d[1], 0.f));
    u.y = pkrtz(fmaxf(d[2], 0.f), fmaxf(d[3], 0.f));
    u.z = pkrtz(fmaxf(d[4], 0.f), fmaxf(d[5], 0.f));
    u.w = pkrtz(fmaxf(d[6], 0.f), fmaxf(d[7], 0.f));
    return __builtin_bit_cast(h8, u);
}

// ---------------- prepack: A fragments with sigma-permuted K axis ------------
// lane l: m = l&31, g = l>>5; element j: k-slot holds source row
// rr = (j&3) + 8*(j>>2) + 4g.
// q=0: layer0 (rows: x0,x1,x2,ones)  q=1: dense(w1,b1)
// q=2+3l/3+3l/4+3l: dense(Wr1,Br1), dense(Wr2,Br2+Br3), W3 (no bias/pass)
// q=32: dense(w8,b8)   q=33: out row m=0: w9 / b9
__global__ __launch_bounds__(256) void prepack(
    const float* __restrict__ w0, const float* __restrict__ b0,
    const float* __restrict__ w1, const float* __restrict__ b1,
    const float* __restrict__ Wr1, const float* __restrict__ Br1,
    const float* __restrict__ Wr2, const float* __restrict__ Br2,
    const float* __restrict__ Wr3, const float* __restrict__ Br3,
    const float* __restrict__ w8, const float* __restrict__ b8,
    const float* __restrict__ w9, const float* __restrict__ b9,
    h8* __restrict__ tab)
{
    for (int e = threadIdx.x; e < NMM * 64; e += 256) {
        const int q = e >> 6, l = e & 63;
        const int m = l & 31, g = l >> 5;
        h8 v;
#pragma unroll
        for (int j = 0; j < 8; ++j) {
            const int rr = (j & 3) + 8 * (j >> 2) + 4 * g;  // sigma(k)
            float a = 0.0f;
            if (q == 0) {
                if (m < 10 && rr < 3)        a = w0[rr * 10 + m];
                else if (m < 10 && rr == 3)  a = b0[m];
                else if (m == 10 && rr == 3) a = 1.0f;
            } else if (q == 33) {
                if (m == 0 && rr < 10)       a = w9[rr];
                else if (m == 0 && rr == 10) a = b9[0];
            } else {
                const float* W = nullptr;
                float bias = 0.0f;
                bool hasB = true, pass = true;
                if (q == 1)       { W = w1; bias = (m < 10) ? b1[m] : 0.0f; }
                else if (q == 32) { W = w8; bias = (m < 10) ? b8[m] : 0.0f; }
                else {
                    const int qq = q - 2, bl = qq / 3, r = qq % 3;
                    if (r == 0)      { W = Wr1 + bl * 100; bias = (m < 10) ? Br1[bl * 10 + m] : 0.0f; }
                    else if (r == 1) { W = Wr2 + bl * 100; bias = (m < 10) ? Br2[bl * 10 + m] + Br3[bl * 10 + m] : 0.0f; }
                    else             { W = Wr3 + bl * 100; hasB = false; pass = false; }
                }
                if (m < 10 && rr < 10)                a = W[rr * 10 + m];
                else if (m < 10 && rr == 10 && hasB)  a = bias;
                else if (m == 10 && rr == 10 && pass) a = 1.0f;
            }
            v[j] = (_Float16)a;
        }
        tab[e] = v;
    }
}

// ---------------- main kernel: 32-point tiles, 2 chains ----------------------
__global__ __launch_bounds__(256, 2) void resnet_fwd(
    const float* __restrict__ x,
    const h8* __restrict__ tab,
    float* __restrict__ out)
{
    const int lane = threadIdx.x & 63;
    const int wv = blockIdx.x * 4 + (threadIdx.x >> 6);
    const int col = lane & 31;
    const bool lo = lane < 32;

    // weight fragments: per-lane addresses, loaded once (34 x 16B/lane)
    h8 wA[NMM];
#pragma unroll
    for (int q = 0; q < NMM; ++q) wA[q] = tab[q * 64 + lane];

    v16f zero;
#pragma unroll
    for (int j = 0; j < 16; ++j) zero[j] = 0.0f;

    const long tile0 = (long)wv * TPW;

    for (int t = 0; t < TPW; t += ILP) {
        long base[ILP];
        h8 hh[ILP];

        // layer-0 B: lanes 0-31 carry (x0,x1,x2,1) in rows 0-3; rest zero
#pragma unroll
        for (int c = 0; c < ILP; ++c) {
            base[c] = (tile0 + t + c) * 32;
            float a0 = 0.f, a1 = 0.f, a2 = 0.f, a3 = 0.f;
            if (lo) {
                const float* p = x + (base[c] + col) * 3;
                a0 = p[0]; a1 = p[1]; a2 = p[2]; a3 = 1.0f;
            }
            u4v u;
            u.x = pkrtz(a0, a1);
            u.y = pkrtz(a2, a3);
            u.z = 0u; u.w = 0u;
            hh[c] = __builtin_bit_cast(h8, u);
        }

        // layer 0, layer 1
#pragma unroll
        for (int c = 0; c < ILP; ++c) hh[c] = rc(mm(wA[0], hh[c], zero));
#pragma unroll
        for (int c = 0; c < ILP; ++c) hh[c] = rc(mm(wA[1], hh[c], zero));

        // residual blocks (unrolled: wA indices constant)
#pragma unroll
        for (int bl = 0; bl < 10; ++bl) {
            v16f d1[ILP], d2[ILP];
#pragma unroll
            for (int c = 0; c < ILP; ++c) d1[c] = mm(wA[2 + 3 * bl], hh[c], zero);
#pragma unroll
            for (int c = 0; c < ILP; ++c) d2[c] = mm(wA[3 + 3 * bl], hh[c], zero);
#pragma unroll
            for (int c = 0; c < ILP; ++c) {
                h8 t1 = rc(d1[c]);
                d2[c] = mm(wA[4 + 3 * bl], t1, d2[c]);
            }
#pragma unroll
            for (int c = 0; c < ILP; ++c) hh[c] = rc(d2[c]);
        }

        // layer 8
#pragma unroll
        for (int c = 0; c < ILP; ++c) hh[c] = rc(mm(wA[32], hh[c], zero));

        // output layer: D row 0 (lanes 0-31, reg 0) = result for 32 points
#pragma unroll
        for (int c = 0; c < ILP; ++c) {
            v16f d = mm(wA[33], hh[c], zero);
            if (lo) out[base[c] + col] = d[0];
        }
    }
}

extern "C" void kernel_launch(void* const* d_in, const int* in_sizes, int n_in,
                              void* d_out, int out_size, void* d_ws, size_t ws_size,
                              hipStream_t stream)
{
    const float* x   = (const float*)d_in[0];
    const float* w0  = (const float*)d_in[1];
    const float* b0  = (const float*)d_in[2];
    const float* w1  = (const float*)d_in[3];
    const float* b1  = (const float*)d_in[4];
    const float* Wr1 = (const float*)d_in[5];
    const float* Br1 = (const float*)d_in[6];
    const float* Wr2 = (const float*)d_in[7];
    const float* Br2 = (const float*)d_in[8];
    const float* Wr3 = (const float*)d_in[9];
    const float* Br3 = (const float*)d_in[10];
    const float* w8  = (const float*)d_in[11];
    const float* b8  = (const float*)d_in[12];
    const float* w9  = (const float*)d_in[13];
    const float* b9  = (const float*)d_in[14];
    float* out = (float*)d_out;
    h8* tab = (h8*)d_ws;   // 34 * 64 * 16B = 34.8 KB scratch

    hipLaunchKernelGGL(prepack, dim3(1), dim3(256), 0, stream,
                       w0, b0, w1, b1, Wr1, Br1, Wr2, Br2, Wr3, Br3,
                       w8, b8, w9, b9, tab);

    hipLaunchKernelGGL(resnet_fwd, dim3(NBLK), dim3(256), 0, stream,
                       x, (const h8*)tab, out);
}